// Round 2
// 713.651 us; speedup vs baseline: 1.0129x; 1.0129x over previous
//
#include <hip/hip_runtime.h>
#include <float.h>
#include <stdint.h>

#define NEG_POS_RATIO 3
#define MAXM 64
#define CHUNK 1024   // anchors per block in matching kernels (4 per thread)

__device__ __forceinline__ float smooth_l1(float d) {
    float a = fabsf(d);
    return a < 1.0f ? 0.5f * a * a : a - 0.5f;
}
// order-preserving float->uint key (ascending float -> ascending uint)
__device__ __forceinline__ unsigned key_of(float f) {
    unsigned u = __float_as_uint(f);
    return (u & 0x80000000u) ? ~u : (u | 0x80000000u);
}
__device__ __forceinline__ float val_of(unsigned k) {
    return __uint_as_float((k & 0x80000000u) ? (k ^ 0x80000000u) : ~k);
}

// ---------------------------------------------------------------------------
// K0: init accumulators (ws is poisoned 0xAA before every launch)
// ---------------------------------------------------------------------------
__global__ void __launch_bounds__(256) k_init(
    unsigned long long* __restrict__ gbest, float* __restrict__ loc_loss,
    float* __restrict__ pos_conf, int* __restrict__ n_pos, int BM, int B)
{
    const int t = blockIdx.x * blockDim.x + threadIdx.x;
    if (t < BM) gbest[t] = 0ULL;
    if (t < B) { loc_loss[t] = 0.0f; pos_conf[t] = 0.0f; n_pos[t] = 0; }
}

// ---------------------------------------------------------------------------
// K1a: per-GT best anchor (global u64 atomicMax; first-index tiebreak ~a)
// grid (NCHUNK, B)
// ---------------------------------------------------------------------------
__global__ void __launch_bounds__(256) k_gtbest(
    const float*  __restrict__ gt_boxes,   // B*M*4 xyxy
    const float4* __restrict__ anchors,    // A cxcywh
    int A, int M,
    unsigned long long* __restrict__ gbest) // B*M
{
    const int b = blockIdx.y, tid = threadIdx.x;
    const int base = blockIdx.x * CHUNK;
    __shared__ float              s_gt[MAXM * 4];
    __shared__ unsigned long long s_best[MAXM];
    if (tid < M * 4) s_gt[tid] = gt_boxes[(size_t)b * M * 4 + tid];
    if (tid < M) s_best[tid] = 0ULL;
    __syncthreads();

    float ax1[4], ay1[4], ax2[4], ay2[4], aarea[4];
    bool  val[4];
#pragma unroll
    for (int i = 0; i < 4; ++i) {
        const int a = base + tid + i * 256;
        val[i] = a < A;
        if (val[i]) {
            const float4 an = anchors[a];
            const float hx = an.z * 0.5f, hy = an.w * 0.5f;
            ax1[i] = an.x - hx; ay1[i] = an.y - hy;
            ax2[i] = an.x + hx; ay2[i] = an.y + hy;
            aarea[i] = an.z * an.w;
        } else { ax1[i]=ay1[i]=ax2[i]=ay2[i]=aarea[i]=0.0f; }
    }
    for (int j = 0; j < M; ++j) {
        const float gx1 = s_gt[4*j+0], gy1 = s_gt[4*j+1];
        const float gx2 = s_gt[4*j+2], gy2 = s_gt[4*j+3];
        const float garea = (gx2 - gx1) * (gy2 - gy1);
        unsigned long long best = 0ULL;
#pragma unroll
        for (int i = 0; i < 4; ++i) {
            if (!val[i]) continue;
            const float w = fmaxf(fminf(gx2, ax2[i]) - fmaxf(gx1, ax1[i]), 0.0f);
            const float h = fmaxf(fminf(gy2, ay2[i]) - fmaxf(gy1, ay1[i]), 0.0f);
            const float inter = w * h;
            const float iou = inter / ((garea + aarea[i] - inter) + 1e-7f);
            const unsigned a_idx = (unsigned)(base + tid + i * 256);
            const unsigned long long pk =
                ((unsigned long long)__float_as_uint(iou) << 32)
              | (unsigned long long)(0xFFFFFFFFu - a_idx);
            if (pk > best) best = pk;
        }
#pragma unroll
        for (int off = 32; off; off >>= 1) {
            const unsigned long long o = __shfl_xor(best, off);
            if (o > best) best = o;
        }
        if ((tid & 63) == 0) atomicMax(&s_best[j], best);
    }
    __syncthreads();
    if (tid < M) atomicMax(&gbest[(size_t)b * M + tid], s_best[tid]);
}

// ---------------------------------------------------------------------------
// K1b: per-anchor best GT + force-assign replay + loc loss + class targets
// grid (NCHUNK, B)
// ---------------------------------------------------------------------------
__global__ void __launch_bounds__(256) k_assign(
    const float4* __restrict__ pred_locs,  // B*A float4
    const float*  __restrict__ gt_boxes,
    const int*    __restrict__ gt_labels,
    const float4* __restrict__ anchors,
    int A, int M,
    const unsigned long long* __restrict__ gbest,
    float* __restrict__ loc_loss, int* __restrict__ n_pos,
    int* __restrict__ cls_out)
{
    const int b = blockIdx.y, tid = threadIdx.x;
    const int base = blockIdx.x * CHUNK;
    __shared__ float s_gt[MAXM * 4];
    __shared__ int   s_lab[MAXM];
    __shared__ float s_gbi[MAXM];
    __shared__ int   s_gbx[MAXM];
    if (tid < M * 4) s_gt[tid] = gt_boxes[(size_t)b * M * 4 + tid];
    if (tid < M) {
        s_lab[tid] = gt_labels[(size_t)b * M + tid];
        const unsigned long long v = gbest[(size_t)b * M + tid];
        s_gbi[tid] = __uint_as_float((unsigned)(v >> 32));
        s_gbx[tid] = (int)(0xFFFFFFFFu - (unsigned)(v & 0xFFFFFFFFull));
    }
    __syncthreads();

    float lsum = 0.0f;
    int   np   = 0;
#pragma unroll
    for (int i = 0; i < 4; ++i) {
        const int a = base + tid + i * 256;
        if (a >= A) continue;
        const float4 an = anchors[a];
        const float hx = an.z * 0.5f, hy = an.w * 0.5f;
        const float ax1 = an.x - hx, ay1 = an.y - hy;
        const float ax2 = an.x + hx, ay2 = an.y + hy;
        const float aarea = an.z * an.w;
        float abest = -1.0f; int aidx = 0;   // argmax-first over j
        for (int j = 0; j < M; ++j) {
            const float gx1 = s_gt[4*j+0], gy1 = s_gt[4*j+1];
            const float gx2 = s_gt[4*j+2], gy2 = s_gt[4*j+3];
            const float garea = (gx2 - gx1) * (gy2 - gy1);
            const float w = fmaxf(fminf(gx2, ax2) - fmaxf(gx1, ax1), 0.0f);
            const float h = fmaxf(fminf(gy2, ay2) - fmaxf(gy1, ay1), 0.0f);
            const float inter = w * h;
            const float iou = inter / ((garea + aarea - inter) + 1e-7f);
            if (iou > abest) { abest = iou; aidx = j; }
        }
        bool pos = abest > 0.5f;
        int midx = aidx;
        // sequential force-assignment replay (ascending j, ORIGINAL abest)
        for (int j = 0; j < M; ++j) {
            if (s_gbx[j] == a && s_gbi[j] > 1e-5f) {
                pos = true;
                if (abest < s_gbi[j]) midx = j;
            }
        }
        int cls = 0;
        if (pos) {
            const float gx1 = s_gt[4*midx+0], gy1 = s_gt[4*midx+1];
            const float gx2 = s_gt[4*midx+2], gy2 = s_gt[4*midx+3];
            const float mcx = (gx1 + gx2) * 0.5f, mcy = (gy1 + gy2) * 0.5f;
            const float mw = gx2 - gx1, mh = gy2 - gy1;
            const float e0 = (mcx - an.x) / an.z;
            const float e1 = (mcy - an.y) / an.w;
            const float e2 = logf(mw / an.z + 1e-7f);
            const float e3 = logf(mh / an.w + 1e-7f);
            const float4 p = pred_locs[(size_t)b * A + a];
            lsum += smooth_l1(p.x - e0) + smooth_l1(p.y - e1)
                  + smooth_l1(p.z - e2) + smooth_l1(p.w - e3);
            ++np;
            cls = s_lab[midx] + 1;
        }
        cls_out[(size_t)b * A + a] = cls;
    }
#pragma unroll
    for (int off = 32; off; off >>= 1) {
        lsum += __shfl_xor(lsum, off);
        np   += __shfl_xor(np, off);
    }
    if ((tid & 63) == 0) {
        atomicAdd(&loc_loss[b], lsum);
        atomicAdd(&n_pos[b], np);
    }
}

// ---------------------------------------------------------------------------
// K2 (C==81, total%64==0 specialization): LDS-staged, float4-coalesced CE.
// 64 rows/block: 64*81 floats = 64*324 B = 20736 B = exactly 1296 float4
// (16B-aligned per block since 20736 % 16 == 0). Stage with 6 independent
// float4 loads/thread (perfectly coalesced, ~6 KB/wave in flight -> the
// m13-style streaming pattern that reaches ~6.3 TB/s), then 4 lanes/row
// compute from LDS (stride-4 columns: bank = 17*row+sub4+4k mod 32 ~ 2-way,
// free). Same math as before: -log_softmax[c] = log(sum exp) - score[c].
// ---------------------------------------------------------------------------
__global__ void __launch_bounds__(256) k_conf81v2(
    const float* __restrict__ scores,   // total*81
    const int*   __restrict__ cls_arr,  // total
    float* __restrict__ pos_conf,       // B
    unsigned* __restrict__ keys,        // total (0 for positives)
    int A, int total)
{
    __shared__ float lds[64 * 81];                 // 20736 B
    const int tid   = threadIdx.x;
    const int first = blockIdx.x * 64;

    // ---- stage: 1296 float4 per block, coalesced ----
    const float4* src4 = (const float4*)scores + (size_t)blockIdx.x * 1296;
    float4 v[5];
#pragma unroll
    for (int k = 0; k < 5; ++k) v[k] = src4[tid + k * 256];
    float4 vt = make_float4(0.f, 0.f, 0.f, 0.f);
    if (tid < 16) vt = src4[1280 + tid];

    const int row_l = tid >> 2;                    // 0..63
    const int sub4  = tid & 3;
    const int c = cls_arr[first + row_l];          // broadcast load, issued early

    float4* lds4 = (float4*)lds;
#pragma unroll
    for (int k = 0; k < 5; ++k) lds4[tid + k * 256] = v[k];
    if (tid < 16) lds4[1280 + tid] = vt;
    __syncthreads();

    // ---- compute: 4 lanes per row, stride-4 columns ----
    const float* rp = lds + row_l * 81;
    float s = 0.0f, t = -FLT_MAX;
#pragma unroll
    for (int k = 0; k < 20; ++k) {
        const int idx = sub4 + 4 * k;              // covers 0..79
        const float val = rp[idx];
        s += __expf(val);
        t = (idx == c) ? val : t;
    }
    if (sub4 == 0) {                               // column 80
        const float val = rp[80];
        s += __expf(val);
        t = (c == 80) ? val : t;
    }
    s += __shfl_xor(s, 1);  t = fmaxf(t, __shfl_xor(t, 1));
    s += __shfl_xor(s, 2);  t = fmaxf(t, __shfl_xor(t, 2));

    if (sub4 == 0) {
        const int row = first + row_l;
        const float conf = __logf(s) - t;          // = -log_softmax[cls]
        if (c > 0) {
            atomicAdd(&pos_conf[row / A], conf);
            keys[row] = 0u;                        // positives never selected
        } else {
            keys[row] = key_of(conf);
        }
    }
}

// ---------------------------------------------------------------------------
// K2 fallback (C==81, total not 64-divisible): register-only, 16 lanes/row.
// ---------------------------------------------------------------------------
__global__ void __launch_bounds__(256) k_conf81(
    const float* __restrict__ scores,   // total*81
    const int*   __restrict__ cls_arr,  // total
    float* __restrict__ pos_conf,       // B
    unsigned* __restrict__ keys,        // total (0 for positives)
    int A, int total)
{
    const int tid  = threadIdx.x;
    const int wav  = tid >> 6;
    const int lane = tid & 63;
    const int sub  = lane & 15;
    const int row  = (blockIdx.x * 4 + wav) * 4 + (lane >> 4);
    if (row >= total) return;            // uniform across each 16-lane group

    const float* rp = scores + (size_t)row * 81;
    const int c = cls_arr[row];          // independent load, issued early
    const float v0 = rp[sub];
    const float v1 = rp[sub + 16];
    const float v2 = rp[sub + 32];
    const float v3 = rp[sub + 48];
    const float v4 = rp[sub + 64];
    float v5 = 0.0f;
    const bool has5 = (sub == 0);
    if (has5) v5 = rp[80];

    float s = __expf(v0) + __expf(v1) + __expf(v2) + __expf(v3) + __expf(v4);
    if (has5) s += __expf(v5);
    float t = -FLT_MAX;
    t = (sub      == c) ? v0 : t;
    t = (sub + 16 == c) ? v1 : t;
    t = (sub + 32 == c) ? v2 : t;
    t = (sub + 48 == c) ? v3 : t;
    t = (sub + 64 == c) ? v4 : t;
    if (has5 && c == 80) t = v5;
#pragma unroll
    for (int off = 8; off; off >>= 1) {   // stays within the 16-lane group
        s += __shfl_xor(s, off);
        t  = fmaxf(t, __shfl_xor(t, off));
    }
    if (sub == 0) {
        const float conf = __logf(s) - t;   // = -log_softmax[cls]
        if (c > 0) {
            atomicAdd(&pos_conf[row / A], conf);
            keys[row] = 0u;                  // positives rank last, never selected
        } else {
            keys[row] = key_of(conf);
        }
    }
}

// Generic-C fallback (R3 structure): 16 lanes/row strided loop.
__global__ void __launch_bounds__(256) k_conf_gen(
    const float* __restrict__ scores, const int* __restrict__ cls_arr,
    float* __restrict__ pos_conf, unsigned* __restrict__ keys,
    int A, int C, int total)
{
    const int tid  = threadIdx.x;
    const int lane = tid & 63;
    const int sub  = lane & 15;
    const int row  = (blockIdx.x * 4 + (tid >> 6)) * 4 + (lane >> 4);
    float s = 0.0f, sc = -FLT_MAX;
    int cls = 0;
    const bool active = row < total;
    if (active) {
        cls = cls_arr[row];
        const float* rpp = scores + (size_t)row * C;
        for (int idx = sub; idx < C; idx += 16) {
            const float v = rpp[idx];
            s += __expf(v);
            if (idx == cls) sc = v;
        }
    }
#pragma unroll
    for (int off = 8; off; off >>= 1) {
        s  += __shfl_xor(s, off);
        sc  = fmaxf(sc, __shfl_xor(sc, off));
    }
    if (active && sub == 0) {
        const float conf = __logf(s) - sc;
        if (cls > 0) { atomicAdd(&pos_conf[row / A], conf); keys[row] = 0u; }
        else keys[row] = key_of(conf);
    }
}

// ---------------------------------------------------------------------------
// K3: per-batch top-k sum of negative CE via 4x8-bit radix select.
// 1024 threads; unrolled predicated uint4 gathers (independent loads in
// flight). Ballot-aggregated histogram: one atomic per distinct bin per wave.
// ---------------------------------------------------------------------------
__device__ __forceinline__ void hist_add(
    int* hist, unsigned key, unsigned pref, int shift, bool first, int lane,
    bool valid)
{
    const bool ok = valid &&
        (first || ((key >> (shift + 8)) == (pref >> (shift + 8))));
    if (ok) {
        const int bin = (key >> shift) & 255;
        unsigned long long mm = __ballot(1);
#pragma unroll
        for (int bit = 0; bit < 8; ++bit) {
            const unsigned long long bb = __ballot((bin >> bit) & 1);
            mm &= ((bin >> bit) & 1) ? bb : ~bb;
        }
        if ((mm & ((1ULL << lane) - 1)) == 0)       // leader lane
            atomicAdd(&hist[bin], (int)__popcll(mm));
    }
}

__global__ void __launch_bounds__(1024) k_select(
    const unsigned* __restrict__ keys, const int* __restrict__ n_pos,
    float* __restrict__ neg_conf, int A, int M)
{
    const int b    = blockIdx.x;
    const int tid  = threadIdx.x;
    const int lane = tid & 63;
    const unsigned* kb = keys + (size_t)b * A;
    const int np = n_pos[b];
    const int k = (np > 0) ? min(NEG_POS_RATIO * np, A - np)
                           : min(NEG_POS_RATIO * M, A);
    __shared__ int      hist[256];
    __shared__ unsigned s_pref;
    __shared__ int      s_rem;
    if (k <= 0) { if (tid == 0) neg_conf[b] = 0.0f; return; }
    if (tid == 0) { s_pref = 0u; s_rem = k; }

    const int A4   = A >> 2;
    const int tail = A - (A4 << 2);
    const uint4* kb4 = (const uint4*)kb;
    __syncthreads();

    for (int pass = 0; pass < 4; ++pass) {
        const int shift = 24 - 8 * pass;
        if (tid < 256) hist[tid] = 0;
        __syncthreads();
        const unsigned pref = s_pref;
        const bool first = (pass == 0);
        for (int base = 0; base < A4; base += 8 * 1024) {
            uint4 kk[8]; bool ok[8];
#pragma unroll
            for (int u = 0; u < 8; ++u) {       // independent predicated loads
                const int i = base + tid + u * 1024;
                ok[u] = (i < A4);
                kk[u] = ok[u] ? kb4[i] : uint4{0, 0, 0, 0};
            }
#pragma unroll
            for (int u = 0; u < 8; ++u) {
                hist_add(hist, kk[u].x, pref, shift, first, lane, ok[u]);
                hist_add(hist, kk[u].y, pref, shift, first, lane, ok[u]);
                hist_add(hist, kk[u].z, pref, shift, first, lane, ok[u]);
                hist_add(hist, kk[u].w, pref, shift, first, lane, ok[u]);
            }
        }
        if (tid < tail) hist_add(hist, kb[(A4 << 2) + tid], pref, shift, first,
                                 lane, true);
        __syncthreads();
        if (tid == 0) {
            int rem = s_rem, cum = 0, bsel = 0;
            for (int i = 255; i >= 0; --i) {
                const int c = hist[i];
                if (cum + c >= rem) { bsel = i; s_rem = rem - cum; break; }
                cum += c;
            }
            s_pref = pref | ((unsigned)bsel << shift);
        }
        __syncthreads();
    }
    const unsigned kth = s_pref;   // exact key of the k-th largest element
    float sum = 0.0f; int cnt = 0;
    for (int base = 0; base < A4; base += 8 * 1024) {
        uint4 kk[8]; bool ok[8];
#pragma unroll
        for (int u = 0; u < 8; ++u) {
            const int i = base + tid + u * 1024;
            ok[u] = (i < A4);
            kk[u] = ok[u] ? kb4[i] : uint4{0, 0, 0, 0};   // key 0 never > kth
        }
#pragma unroll
        for (int u = 0; u < 8; ++u) {
            if (kk[u].x > kth) { sum += val_of(kk[u].x); ++cnt; }
            if (kk[u].y > kth) { sum += val_of(kk[u].y); ++cnt; }
            if (kk[u].z > kth) { sum += val_of(kk[u].z); ++cnt; }
            if (kk[u].w > kth) { sum += val_of(kk[u].w); ++cnt; }
        }
    }
    if (tid < tail) {
        const unsigned key = kb[(A4 << 2) + tid];
        if (key > kth) { sum += val_of(key); ++cnt; }
    }
#pragma unroll
    for (int off = 32; off; off >>= 1) {
        sum += __shfl_xor(sum, off);
        cnt += __shfl_xor(cnt, off);
    }
    __shared__ float s_sum[16];
    __shared__ int   s_cnt[16];
    const int w = tid >> 6;
    if (lane == 0) { s_sum[w] = sum; s_cnt[w] = cnt; }
    __syncthreads();
    if (tid == 0) {
        float ts = 0.0f; int tc = 0;
        const int nw = (int)(blockDim.x >> 6);
        for (int i = 0; i < nw; ++i) { ts += s_sum[i]; tc += s_cnt[i]; }
        neg_conf[b] = ts + (float)(k - tc) * val_of(kth);
    }
}

// ---------------------------------------------------------------------------
// K4: finalize 3 scalar outputs (parallel across batch, wave-reduce)
// ---------------------------------------------------------------------------
__global__ void __launch_bounds__(64) k_final(
    const float* __restrict__ loc_loss,
    const float* __restrict__ pos_conf,
    const float* __restrict__ neg_conf,
    const int*   __restrict__ n_pos,
    int B, float* __restrict__ out)
{
    const int tid = threadIdx.x;
    float L = 0.0f, Cs = 0.0f;
    int   np = 0;
    for (int b = tid; b < B; b += 64) {
        L  += loc_loss[b];
        Cs += pos_conf[b] + neg_conf[b];
        np += n_pos[b];
    }
#pragma unroll
    for (int off = 32; off; off >>= 1) {
        L  += __shfl_xor(L, off);
        Cs += __shfl_xor(Cs, off);
        np += __shfl_xor(np, off);
    }
    if (tid == 0) {
        const float denom = (float)(np > 1 ? np : 1);
        out[0] = (L + Cs) / denom;
        out[1] = L / denom;
        out[2] = Cs / denom;
    }
}

extern "C" void kernel_launch(void* const* d_in, const int* in_sizes, int n_in,
                              void* d_out, int out_size, void* d_ws, size_t ws_size,
                              hipStream_t stream) {
    const float* pred_locs = (const float*)d_in[0];
    const float* scores    = (const float*)d_in[1];
    const float* gt_boxes  = (const float*)d_in[2];
    const int*   gt_labels = (const int*)d_in[3];
    const float* anchors   = (const float*)d_in[4];

    const int A = in_sizes[4] / 4;
    const int B = (int)((long long)in_sizes[0] / (4LL * A));
    const int M = in_sizes[3] / B;
    const int C = (int)((long long)in_sizes[1] / ((long long)B * A));
    float* out = (float*)d_out;

    // ws layout: [loc_loss B][pos_conf B][neg_conf B][n_pos B] | gbest B*M u64 | cls B*A | keys B*A
    char* ws = (char*)d_ws;
    float* loc_loss = (float*)ws;
    float* pos_conf = loc_loss + B;
    float* neg_conf = pos_conf + B;
    int*   n_pos    = (int*)(neg_conf + B);
    size_t off = (size_t)(((16LL * B) + 255) / 256) * 256;
    unsigned long long* gbest = (unsigned long long*)(ws + off);
    off += (size_t)(((8LL * B * M) + 255) / 256) * 256;
    int*      cls_arr = (int*)(ws + off);
    unsigned* keys    = (unsigned*)(ws + off + (size_t)B * A * sizeof(int));

    const int NCHUNK = (A + CHUNK - 1) / CHUNK;

    k_init<<<(B * M + 255) / 256, 256, 0, stream>>>(gbest, loc_loss, pos_conf, n_pos,
                                                    B * M, B);
    k_gtbest<<<dim3(NCHUNK, B), 256, 0, stream>>>(gt_boxes, (const float4*)anchors,
                                                  A, M, gbest);
    k_assign<<<dim3(NCHUNK, B), 256, 0, stream>>>((const float4*)pred_locs, gt_boxes,
                                                  gt_labels, (const float4*)anchors,
                                                  A, M, gbest, loc_loss, n_pos, cls_arr);

    const int total = (int)((long long)B * A);
    if (C == 81 && (total & 63) == 0) {
        k_conf81v2<<<dim3((unsigned)(total / 64)), 256, 0, stream>>>(
            scores, cls_arr, pos_conf, keys, A, total);
    } else if (C == 81) {
        const int nblk = (total + 15) / 16;
        k_conf81<<<dim3((unsigned)nblk), 256, 0, stream>>>(scores, cls_arr, pos_conf,
                                                           keys, A, total);
    } else {
        const int nblk = (total + 15) / 16;
        k_conf_gen<<<dim3((unsigned)nblk), 256, 0, stream>>>(scores, cls_arr, pos_conf,
                                                             keys, A, C, total);
    }

    k_select<<<B, 1024, 0, stream>>>(keys, n_pos, neg_conf, A, M);

    k_final<<<1, 64, 0, stream>>>(loc_loss, pos_conf, neg_conf, n_pos, B, out);
}

// Round 5
// 664.685 us; speedup vs baseline: 1.0875x; 1.0737x over previous
//
#include <hip/hip_runtime.h>
#include <float.h>
#include <stdint.h>

#define NEG_POS_RATIO 3
#define MAXM 64
#define CHUNK 1024   // anchors per block in matching kernels (4 per thread)

__device__ __forceinline__ float smooth_l1(float d) {
    float a = fabsf(d);
    return a < 1.0f ? 0.5f * a * a : a - 0.5f;
}
// order-preserving float->uint key (ascending float -> ascending uint)
__device__ __forceinline__ unsigned key_of(float f) {
    unsigned u = __float_as_uint(f);
    return (u & 0x80000000u) ? ~u : (u | 0x80000000u);
}
__device__ __forceinline__ float val_of(unsigned k) {
    return __uint_as_float((k & 0x80000000u) ? (k ^ 0x80000000u) : ~k);
}

// ---------------------------------------------------------------------------
// K0: init accumulators (ws is poisoned 0xAA before every launch)
// ---------------------------------------------------------------------------
__global__ void __launch_bounds__(256) k_init(
    unsigned long long* __restrict__ gbest, float* __restrict__ loc_loss,
    float* __restrict__ pos_conf, int* __restrict__ n_pos, int BM, int B)
{
    const int t = blockIdx.x * blockDim.x + threadIdx.x;
    if (t < BM) gbest[t] = 0ULL;
    if (t < B) { loc_loss[t] = 0.0f; pos_conf[t] = 0.0f; n_pos[t] = 0; }
}

// ---------------------------------------------------------------------------
// K1a: per-GT best anchor (global u64 atomicMax; first-index tiebreak ~a)
// grid (NCHUNK, B)
// ---------------------------------------------------------------------------
__global__ void __launch_bounds__(256) k_gtbest(
    const float*  __restrict__ gt_boxes,   // B*M*4 xyxy
    const float4* __restrict__ anchors,    // A cxcywh
    int A, int M,
    unsigned long long* __restrict__ gbest) // B*M
{
    const int b = blockIdx.y, tid = threadIdx.x;
    const int base = blockIdx.x * CHUNK;
    __shared__ float              s_gt[MAXM * 4];
    __shared__ unsigned long long s_best[MAXM];
    if (tid < M * 4) s_gt[tid] = gt_boxes[(size_t)b * M * 4 + tid];
    if (tid < M) s_best[tid] = 0ULL;
    __syncthreads();

    float ax1[4], ay1[4], ax2[4], ay2[4], aarea[4];
    bool  val[4];
#pragma unroll
    for (int i = 0; i < 4; ++i) {
        const int a = base + tid + i * 256;
        val[i] = a < A;
        if (val[i]) {
            const float4 an = anchors[a];
            const float hx = an.z * 0.5f, hy = an.w * 0.5f;
            ax1[i] = an.x - hx; ay1[i] = an.y - hy;
            ax2[i] = an.x + hx; ay2[i] = an.y + hy;
            aarea[i] = an.z * an.w;
        } else { ax1[i]=ay1[i]=ax2[i]=ay2[i]=aarea[i]=0.0f; }
    }
    for (int j = 0; j < M; ++j) {
        const float gx1 = s_gt[4*j+0], gy1 = s_gt[4*j+1];
        const float gx2 = s_gt[4*j+2], gy2 = s_gt[4*j+3];
        const float garea = (gx2 - gx1) * (gy2 - gy1);
        unsigned long long best = 0ULL;
#pragma unroll
        for (int i = 0; i < 4; ++i) {
            if (!val[i]) continue;
            const float w = fmaxf(fminf(gx2, ax2[i]) - fmaxf(gx1, ax1[i]), 0.0f);
            const float h = fmaxf(fminf(gy2, ay2[i]) - fmaxf(gy1, ay1[i]), 0.0f);
            const float inter = w * h;
            const float iou = inter / ((garea + aarea[i] - inter) + 1e-7f);
            const unsigned a_idx = (unsigned)(base + tid + i * 256);
            const unsigned long long pk =
                ((unsigned long long)__float_as_uint(iou) << 32)
              | (unsigned long long)(0xFFFFFFFFu - a_idx);
            if (pk > best) best = pk;
        }
#pragma unroll
        for (int off = 32; off; off >>= 1) {
            const unsigned long long o = __shfl_xor(best, off);
            if (o > best) best = o;
        }
        if ((tid & 63) == 0) atomicMax(&s_best[j], best);
    }
    __syncthreads();
    if (tid < M) atomicMax(&gbest[(size_t)b * M + tid], s_best[tid]);
}

// ---------------------------------------------------------------------------
// K1b: per-anchor best GT + force-assign replay + loc loss + class targets
// grid (NCHUNK, B)
// ---------------------------------------------------------------------------
__global__ void __launch_bounds__(256) k_assign(
    const float4* __restrict__ pred_locs,  // B*A float4
    const float*  __restrict__ gt_boxes,
    const int*    __restrict__ gt_labels,
    const float4* __restrict__ anchors,
    int A, int M,
    const unsigned long long* __restrict__ gbest,
    float* __restrict__ loc_loss, int* __restrict__ n_pos,
    int* __restrict__ cls_out)
{
    const int b = blockIdx.y, tid = threadIdx.x;
    const int base = blockIdx.x * CHUNK;
    __shared__ float s_gt[MAXM * 4];
    __shared__ int   s_lab[MAXM];
    __shared__ float s_gbi[MAXM];
    __shared__ int   s_gbx[MAXM];
    if (tid < M * 4) s_gt[tid] = gt_boxes[(size_t)b * M * 4 + tid];
    if (tid < M) {
        s_lab[tid] = gt_labels[(size_t)b * M + tid];
        const unsigned long long v = gbest[(size_t)b * M + tid];
        s_gbi[tid] = __uint_as_float((unsigned)(v >> 32));
        s_gbx[tid] = (int)(0xFFFFFFFFu - (unsigned)(v & 0xFFFFFFFFull));
    }
    __syncthreads();

    float lsum = 0.0f;
    int   np   = 0;
#pragma unroll
    for (int i = 0; i < 4; ++i) {
        const int a = base + tid + i * 256;
        if (a >= A) continue;
        const float4 an = anchors[a];
        const float hx = an.z * 0.5f, hy = an.w * 0.5f;
        const float ax1 = an.x - hx, ay1 = an.y - hy;
        const float ax2 = an.x + hx, ay2 = an.y + hy;
        const float aarea = an.z * an.w;
        float abest = -1.0f; int aidx = 0;   // argmax-first over j
        for (int j = 0; j < M; ++j) {
            const float gx1 = s_gt[4*j+0], gy1 = s_gt[4*j+1];
            const float gx2 = s_gt[4*j+2], gy2 = s_gt[4*j+3];
            const float garea = (gx2 - gx1) * (gy2 - gy1);
            const float w = fmaxf(fminf(gx2, ax2) - fmaxf(gx1, ax1), 0.0f);
            const float h = fmaxf(fminf(gy2, ay2) - fmaxf(gy1, ay1), 0.0f);
            const float inter = w * h;
            const float iou = inter / ((garea + aarea - inter) + 1e-7f);
            if (iou > abest) { abest = iou; aidx = j; }
        }
        bool pos = abest > 0.5f;
        int midx = aidx;
        // sequential force-assignment replay (ascending j, ORIGINAL abest)
        for (int j = 0; j < M; ++j) {
            if (s_gbx[j] == a && s_gbi[j] > 1e-5f) {
                pos = true;
                if (abest < s_gbi[j]) midx = j;
            }
        }
        int cls = 0;
        if (pos) {
            const float gx1 = s_gt[4*midx+0], gy1 = s_gt[4*midx+1];
            const float gx2 = s_gt[4*midx+2], gy2 = s_gt[4*midx+3];
            const float mcx = (gx1 + gx2) * 0.5f, mcy = (gy1 + gy2) * 0.5f;
            const float mw = gx2 - gx1, mh = gy2 - gy1;
            const float e0 = (mcx - an.x) / an.z;
            const float e1 = (mcy - an.y) / an.w;
            const float e2 = logf(mw / an.z + 1e-7f);
            const float e3 = logf(mh / an.w + 1e-7f);
            const float4 p = pred_locs[(size_t)b * A + a];
            lsum += smooth_l1(p.x - e0) + smooth_l1(p.y - e1)
                  + smooth_l1(p.z - e2) + smooth_l1(p.w - e3);
            ++np;
            cls = s_lab[midx] + 1;
        }
        cls_out[(size_t)b * A + a] = cls;
    }
#pragma unroll
    for (int off = 32; off; off >>= 1) {
        lsum += __shfl_xor(lsum, off);
        np   += __shfl_xor(np, off);
    }
    if ((tid & 63) == 0) {
        atomicAdd(&loc_loss[b], lsum);
        atomicAdd(&n_pos[b], np);
    }
}

// ---------------------------------------------------------------------------
// K2 (C==81, total%64==0): PERSISTENT grid-stride CE with one-deep register
// pipeline. R2 showed two opposite access structures both pin at ~840 GB/s
// with all CU pipes idle — suspect: 12282 one-shot blocks each exposing a
// full load->vmcnt(0)->barrier->compute->retire latency chain per 20.7 KB
// tile (m13's 6.3 TB/s proof-point uses persistent grid-stride blocks).
// Here: 2048 persistent blocks, each ~6 tiles; per iteration we write the
// prefetched regs to LDS, barrier, then ISSUE THE NEXT TILE'S LOADS so they
// fly under the current tile's exp/shuffle compute (T14 split, in-wave).
// Same loads, same LDS layout, same math as the R2-verified kernel.
// ---------------------------------------------------------------------------
__global__ void __launch_bounds__(256) k_conf81v3(
    const float* __restrict__ scores,   // total*81
    const int*   __restrict__ cls_arr,  // total
    float* __restrict__ pos_conf,       // B
    unsigned* __restrict__ keys,        // total (0 for positives)
    int A, int ntile)
{
    __shared__ float lds[64 * 81];                 // 20736 B
    const int tid    = threadIdx.x;
    const int row_l  = tid >> 2;                   // 0..63
    const int sub4   = tid & 3;
    const int stride = gridDim.x;

    int tile = blockIdx.x;                         // grid <= ntile guaranteed
    float4 v[5];
    float4 vt = make_float4(0.f, 0.f, 0.f, 0.f);
    {   // prologue: prefetch first tile into registers
        const float4* src4 = (const float4*)scores + (size_t)tile * 1296;
#pragma unroll
        for (int k = 0; k < 5; ++k) v[k] = src4[tid + k * 256];
        if (tid < 16) vt = src4[1280 + tid];
    }
    float4* lds4 = (float4*)lds;

    for (; tile < ntile; tile += stride) {
        __syncthreads();                           // prev compute done; LDS free
#pragma unroll
        for (int k = 0; k < 5; ++k) lds4[tid + k * 256] = v[k];
        if (tid < 16) lds4[1280 + tid] = vt;
        const int c = cls_arr[tile * 64 + row_l];  // broadcast within 4-lane group
        __syncthreads();                           // LDS ready

        const int nxt = tile + stride;             // block-uniform
        if (nxt < ntile) {                         // prefetch next tile NOW:
            const float4* src4 = (const float4*)scores + (size_t)nxt * 1296;
#pragma unroll
            for (int k = 0; k < 5; ++k) v[k] = src4[tid + k * 256];
            if (tid < 16) vt = src4[1280 + tid];
        }

        // ---- compute: 4 lanes per row, stride-4 columns (2-way banks, free)
        const float* rp = lds + row_l * 81;
        float s = 0.0f, t = -FLT_MAX;
#pragma unroll
        for (int k = 0; k < 20; ++k) {
            const int idx = sub4 + 4 * k;          // covers 0..79
            const float val = rp[idx];
            s += __expf(val);
            t = (idx == c) ? val : t;
        }
        if (sub4 == 0) {                           // column 80
            const float val = rp[80];
            s += __expf(val);
            t = (c == 80) ? val : t;
        }
        s += __shfl_xor(s, 1);  t = fmaxf(t, __shfl_xor(t, 1));
        s += __shfl_xor(s, 2);  t = fmaxf(t, __shfl_xor(t, 2));

        if (sub4 == 0) {
            const int row = tile * 64 + row_l;
            const float conf = __logf(s) - t;      // = -log_softmax[cls]
            if (c > 0) {
                atomicAdd(&pos_conf[row / A], conf);
                keys[row] = 0u;                    // positives never selected
            } else {
                keys[row] = key_of(conf);
            }
        }
    }
}

// ---------------------------------------------------------------------------
// K2 fallback (C==81, total not 64-divisible): register-only, 16 lanes/row.
// ---------------------------------------------------------------------------
__global__ void __launch_bounds__(256) k_conf81(
    const float* __restrict__ scores,   // total*81
    const int*   __restrict__ cls_arr,  // total
    float* __restrict__ pos_conf,       // B
    unsigned* __restrict__ keys,        // total (0 for positives)
    int A, int total)
{
    const int tid  = threadIdx.x;
    const int wav  = tid >> 6;
    const int lane = tid & 63;
    const int sub  = lane & 15;
    const int row  = (blockIdx.x * 4 + wav) * 4 + (lane >> 4);
    if (row >= total) return;            // uniform across each 16-lane group

    const float* rp = scores + (size_t)row * 81;
    const int c = cls_arr[row];          // independent load, issued early
    const float v0 = rp[sub];
    const float v1 = rp[sub + 16];
    const float v2 = rp[sub + 32];
    const float v3 = rp[sub + 48];
    const float v4 = rp[sub + 64];
    float v5 = 0.0f;
    const bool has5 = (sub == 0);
    if (has5) v5 = rp[80];

    float s = __expf(v0) + __expf(v1) + __expf(v2) + __expf(v3) + __expf(v4);
    if (has5) s += __expf(v5);
    float t = -FLT_MAX;
    t = (sub      == c) ? v0 : t;
    t = (sub + 16 == c) ? v1 : t;
    t = (sub + 32 == c) ? v2 : t;
    t = (sub + 48 == c) ? v3 : t;
    t = (sub + 64 == c) ? v4 : t;
    if (has5 && c == 80) t = v5;
#pragma unroll
    for (int off = 8; off; off >>= 1) {   // stays within the 16-lane group
        s += __shfl_xor(s, off);
        t  = fmaxf(t, __shfl_xor(t, off));
    }
    if (sub == 0) {
        const float conf = __logf(s) - t;   // = -log_softmax[cls]
        if (c > 0) {
            atomicAdd(&pos_conf[row / A], conf);
            keys[row] = 0u;                  // positives rank last, never selected
        } else {
            keys[row] = key_of(conf);
        }
    }
}

// Generic-C fallback (R3 structure): 16 lanes/row strided loop.
__global__ void __launch_bounds__(256) k_conf_gen(
    const float* __restrict__ scores, const int* __restrict__ cls_arr,
    float* __restrict__ pos_conf, unsigned* __restrict__ keys,
    int A, int C, int total)
{
    const int tid  = threadIdx.x;
    const int lane = tid & 63;
    const int sub  = lane & 15;
    const int row  = (blockIdx.x * 4 + (tid >> 6)) * 4 + (lane >> 4);
    float s = 0.0f, sc = -FLT_MAX;
    int cls = 0;
    const bool active = row < total;
    if (active) {
        cls = cls_arr[row];
        const float* rpp = scores + (size_t)row * C;
        for (int idx = sub; idx < C; idx += 16) {
            const float v = rpp[idx];
            s += __expf(v);
            if (idx == cls) sc = v;
        }
    }
#pragma unroll
    for (int off = 8; off; off >>= 1) {
        s  += __shfl_xor(s, off);
        sc  = fmaxf(sc, __shfl_xor(sc, off));
    }
    if (active && sub == 0) {
        const float conf = __logf(s) - sc;
        if (cls > 0) { atomicAdd(&pos_conf[row / A], conf); keys[row] = 0u; }
        else keys[row] = key_of(conf);
    }
}

// ---------------------------------------------------------------------------
// K3: per-batch top-k sum of negative CE via 4x8-bit radix select.
// 1024 threads; unrolled predicated uint4 gathers (independent loads in
// flight). Ballot-aggregated histogram: one atomic per distinct bin per wave.
// ---------------------------------------------------------------------------
__device__ __forceinline__ void hist_add(
    int* hist, unsigned key, unsigned pref, int shift, bool first, int lane,
    bool valid)
{
    const bool ok = valid &&
        (first || ((key >> (shift + 8)) == (pref >> (shift + 8))));
    if (ok) {
        const int bin = (key >> shift) & 255;
        unsigned long long mm = __ballot(1);
#pragma unroll
        for (int bit = 0; bit < 8; ++bit) {
            const unsigned long long bb = __ballot((bin >> bit) & 1);
            mm &= ((bin >> bit) & 1) ? bb : ~bb;
        }
        if ((mm & ((1ULL << lane) - 1)) == 0)       // leader lane
            atomicAdd(&hist[bin], (int)__popcll(mm));
    }
}

__global__ void __launch_bounds__(1024) k_select(
    const unsigned* __restrict__ keys, const int* __restrict__ n_pos,
    float* __restrict__ neg_conf, int A, int M)
{
    const int b    = blockIdx.x;
    const int tid  = threadIdx.x;
    const int lane = tid & 63;
    const unsigned* kb = keys + (size_t)b * A;
    const int np = n_pos[b];
    const int k = (np > 0) ? min(NEG_POS_RATIO * np, A - np)
                           : min(NEG_POS_RATIO * M, A);
    __shared__ int      hist[256];
    __shared__ unsigned s_pref;
    __shared__ int      s_rem;
    if (k <= 0) { if (tid == 0) neg_conf[b] = 0.0f; return; }
    if (tid == 0) { s_pref = 0u; s_rem = k; }

    const int A4   = A >> 2;
    const int tail = A - (A4 << 2);
    const uint4* kb4 = (const uint4*)kb;
    __syncthreads();

    for (int pass = 0; pass < 4; ++pass) {
        const int shift = 24 - 8 * pass;
        if (tid < 256) hist[tid] = 0;
        __syncthreads();
        const unsigned pref = s_pref;
        const bool first = (pass == 0);
        for (int base = 0; base < A4; base += 8 * 1024) {
            uint4 kk[8]; bool ok[8];
#pragma unroll
            for (int u = 0; u < 8; ++u) {       // independent predicated loads
                const int i = base + tid + u * 1024;
                ok[u] = (i < A4);
                kk[u] = ok[u] ? kb4[i] : uint4{0, 0, 0, 0};
            }
#pragma unroll
            for (int u = 0; u < 8; ++u) {
                hist_add(hist, kk[u].x, pref, shift, first, lane, ok[u]);
                hist_add(hist, kk[u].y, pref, shift, first, lane, ok[u]);
                hist_add(hist, kk[u].z, pref, shift, first, lane, ok[u]);
                hist_add(hist, kk[u].w, pref, shift, first, lane, ok[u]);
            }
        }
        if (tid < tail) hist_add(hist, kb[(A4 << 2) + tid], pref, shift, first,
                                 lane, true);
        __syncthreads();
        if (tid == 0) {
            int rem = s_rem, cum = 0, bsel = 0;
            for (int i = 255; i >= 0; --i) {
                const int c = hist[i];
                if (cum + c >= rem) { bsel = i; s_rem = rem - cum; break; }
                cum += c;
            }
            s_pref = pref | ((unsigned)bsel << shift);
        }
        __syncthreads();
    }
    const unsigned kth = s_pref;   // exact key of the k-th largest element
    float sum = 0.0f; int cnt = 0;
    for (int base = 0; base < A4; base += 8 * 1024) {
        uint4 kk[8]; bool ok[8];
#pragma unroll
        for (int u = 0; u < 8; ++u) {
            const int i = base + tid + u * 1024;
            ok[u] = (i < A4);
            kk[u] = ok[u] ? kb4[i] : uint4{0, 0, 0, 0};   // key 0 never > kth
        }
#pragma unroll
        for (int u = 0; u < 8; ++u) {
            if (kk[u].x > kth) { sum += val_of(kk[u].x); ++cnt; }
            if (kk[u].y > kth) { sum += val_of(kk[u].y); ++cnt; }
            if (kk[u].z > kth) { sum += val_of(kk[u].z); ++cnt; }
            if (kk[u].w > kth) { sum += val_of(kk[u].w); ++cnt; }
        }
    }
    if (tid < tail) {
        const unsigned key = kb[(A4 << 2) + tid];
        if (key > kth) { sum += val_of(key); ++cnt; }
    }
#pragma unroll
    for (int off = 32; off; off >>= 1) {
        sum += __shfl_xor(sum, off);
        cnt += __shfl_xor(cnt, off);
    }
    __shared__ float s_sum[16];
    __shared__ int   s_cnt[16];
    const int w = tid >> 6;
    if (lane == 0) { s_sum[w] = sum; s_cnt[w] = cnt; }
    __syncthreads();
    if (tid == 0) {
        float ts = 0.0f; int tc = 0;
        const int nw = (int)(blockDim.x >> 6);
        for (int i = 0; i < nw; ++i) { ts += s_sum[i]; tc += s_cnt[i]; }
        neg_conf[b] = ts + (float)(k - tc) * val_of(kth);
    }
}

// ---------------------------------------------------------------------------
// K4: finalize 3 scalar outputs (parallel across batch, wave-reduce)
// ---------------------------------------------------------------------------
__global__ void __launch_bounds__(64) k_final(
    const float* __restrict__ loc_loss,
    const float* __restrict__ pos_conf,
    const float* __restrict__ neg_conf,
    const int*   __restrict__ n_pos,
    int B, float* __restrict__ out)
{
    const int tid = threadIdx.x;
    float L = 0.0f, Cs = 0.0f;
    int   np = 0;
    for (int b = tid; b < B; b += 64) {
        L  += loc_loss[b];
        Cs += pos_conf[b] + neg_conf[b];
        np += n_pos[b];
    }
#pragma unroll
    for (int off = 32; off; off >>= 1) {
        L  += __shfl_xor(L, off);
        Cs += __shfl_xor(Cs, off);
        np += __shfl_xor(np, off);
    }
    if (tid == 0) {
        const float denom = (float)(np > 1 ? np : 1);
        out[0] = (L + Cs) / denom;
        out[1] = L / denom;
        out[2] = Cs / denom;
    }
}

extern "C" void kernel_launch(void* const* d_in, const int* in_sizes, int n_in,
                              void* d_out, int out_size, void* d_ws, size_t ws_size,
                              hipStream_t stream) {
    const float* pred_locs = (const float*)d_in[0];
    const float* scores    = (const float*)d_in[1];
    const float* gt_boxes  = (const float*)d_in[2];
    const int*   gt_labels = (const int*)d_in[3];
    const float* anchors   = (const float*)d_in[4];

    const int A = in_sizes[4] / 4;
    const int B = (int)((long long)in_sizes[0] / (4LL * A));
    const int M = in_sizes[3] / B;
    const int C = (int)((long long)in_sizes[1] / ((long long)B * A));
    float* out = (float*)d_out;

    // ws layout: [loc_loss B][pos_conf B][neg_conf B][n_pos B] | gbest B*M u64 | cls B*A | keys B*A
    char* ws = (char*)d_ws;
    float* loc_loss = (float*)ws;
    float* pos_conf = loc_loss + B;
    float* neg_conf = pos_conf + B;
    int*   n_pos    = (int*)(neg_conf + B);
    size_t off = (size_t)(((16LL * B) + 255) / 256) * 256;
    unsigned long long* gbest = (unsigned long long*)(ws + off);
    off += (size_t)(((8LL * B * M) + 255) / 256) * 256;
    int*      cls_arr = (int*)(ws + off);
    unsigned* keys    = (unsigned*)(ws + off + (size_t)B * A * sizeof(int));

    const int NCHUNK = (A + CHUNK - 1) / CHUNK;

    k_init<<<(B * M + 255) / 256, 256, 0, stream>>>(gbest, loc_loss, pos_conf, n_pos,
                                                    B * M, B);
    k_gtbest<<<dim3(NCHUNK, B), 256, 0, stream>>>(gt_boxes, (const float4*)anchors,
                                                  A, M, gbest);
    k_assign<<<dim3(NCHUNK, B), 256, 0, stream>>>((const float4*)pred_locs, gt_boxes,
                                                  gt_labels, (const float4*)anchors,
                                                  A, M, gbest, loc_loss, n_pos, cls_arr);

    const int total = (int)((long long)B * A);
    if (C == 81 && (total & 63) == 0) {
        const int ntile = total / 64;
        const int grid  = ntile < 2048 ? ntile : 2048;   // persistent blocks
        k_conf81v3<<<dim3((unsigned)grid), 256, 0, stream>>>(
            scores, cls_arr, pos_conf, keys, A, ntile);
    } else if (C == 81) {
        const int nblk = (total + 15) / 16;
        k_conf81<<<dim3((unsigned)nblk), 256, 0, stream>>>(scores, cls_arr, pos_conf,
                                                           keys, A, total);
    } else {
        const int nblk = (total + 15) / 16;
        k_conf_gen<<<dim3((unsigned)nblk), 256, 0, stream>>>(scores, cls_arr, pos_conf,
                                                             keys, A, C, total);
    }

    k_select<<<B, 1024, 0, stream>>>(keys, n_pos, neg_conf, A, M);

    k_final<<<1, 64, 0, stream>>>(loc_loss, pos_conf, neg_conf, n_pos, B, out);
}